// Round 1
// baseline (187.518 us; speedup 1.0000x reference)
//
#include <hip/hip_runtime.h>

// Self-attention (SAGAN-style), B=4, C=512, N=4096, O=64.
// Round 12: PV switches to block-scaled MX fp8 (v_mfma_f32_32x32x64_f8f6f4,
//   unit scales = E8M0 127) -> 2x fp8 MFMA rate. PV per wave per nt: 16
//   mfma_32x32x16_fp8 (8cy) -> 4 mfma_scale_32x32x64 (~17cy).
//   - E stays in the SAME m-major Ebuf[m][136] LDS layout: the 64-wide
//     B-frag (lane holds 32 consecutive k of col lane&31, k=(lane>>5)*32+i)
//     reads bytes kt*64 + half*32 + 8j from row lane -- same ds_read_b64
//     count and same bank profile as round 11.
//   - h is now stored ROW-MAJOR fp8 ha[b][c][4096]: the 64-wide A-frag
//     wants 32 consecutive n per lane of one channel row (32B load/lane).
//     proj h-epilogue re-addressed (same 16x 4B stores per thread).
// S phase stays bf16. E' = exp(min(s-6,6)) (e4m3 max 448); the e^-6 scale
// cancels in numerator/denominator.
// Fragment chunk convention (32-row tiles, 16-k chunks, bf16 2B / fp8 1B):
//   chunk[tile][q][lane][i] = M[idx = tile*32 + (lane&31)][k = q*16 + (lane>>5)*8 + i]
// 64-wide MX frag convention: lane holds M[lane&31][k = (lane>>5)*32 + i], i=0..31.

#define N_PIX 4096
#define C_IN  512

typedef __attribute__((ext_vector_type(8)))  short bf16x8;
typedef __attribute__((ext_vector_type(16))) float f32x16;
typedef __attribute__((ext_vector_type(8)))  int   i32x8;

typedef __attribute__((address_space(1))) const unsigned int guint;
typedef __attribute__((address_space(3))) unsigned int luint;

__device__ __forceinline__ void gload_lds16(const void* g, void* l) {
    __builtin_amdgcn_global_load_lds((guint*)g, (luint*)l, 16, 0, 0);
}

__device__ inline unsigned int f2bf(float f) {
    union { float f; unsigned u; } x; x.f = f;
    unsigned r = x.u + 0x7FFFu + ((x.u >> 16) & 1u);
    return r >> 16;
}

__device__ __forceinline__ unsigned cvt_pk_bf16(float a, float b) {
#if __has_builtin(__builtin_amdgcn_cvt_pk_bf16_f32)
    auto r = __builtin_amdgcn_cvt_pk_bf16_f32(a, b);
    unsigned u; __builtin_memcpy(&u, &r, 4); return u;
#else
    return f2bf(a) | (f2bf(b) << 16);
#endif
}

// pack 4 floats -> 4 OCP e4m3 bytes
__device__ __forceinline__ unsigned pk_fp8x4(float a, float b, float c, float d) {
    int v = 0;
    v = __builtin_amdgcn_cvt_pk_fp8_f32(a, b, v, false);
    v = __builtin_amdgcn_cvt_pk_fp8_f32(c, d, v, true);
    return (unsigned)v;
}

// ---------------------------------------------------------------------------
// pack_w (coalesced): grid 20, block 256. Tile tt: 0-1 f_w, 2-3 g_w, 4-19 h_w.
// Weights stay bf16.
__global__ __launch_bounds__(256) void pack_w(
    const float* __restrict__ f_w, const float* __restrict__ g_w,
    const float* __restrict__ h_w, unsigned short* __restrict__ wall)
{
    __shared__ __align__(16) unsigned short Ls[32 * 520];
    const int t  = threadIdx.x;
    const int tt = blockIdx.x;
    const float* W; int rbase;
    if (tt < 2)      { W = f_w; rbase = tt * 32; }
    else if (tt < 4) { W = g_w; rbase = (tt - 2) * 32; }
    else             { W = h_w; rbase = (tt - 4) * 32; }

    #pragma unroll
    for (int k = 0; k < 16; ++k) {
        const int off = (t + k * 256) * 4;
        const int row = off >> 9, col = off & 511;
        float4 v = *(const float4*)&W[(size_t)(rbase + row) * C_IN + col];
        uint2 pk; pk.x = cvt_pk_bf16(v.x, v.y); pk.y = cvt_pk_bf16(v.z, v.w);
        *(uint2*)&Ls[row * 520 + col] = pk;
    }
    __syncthreads();
    #pragma unroll
    for (int j = 0; j < 8; ++j) {
        const int o = t + j * 256;
        const int q = o >> 6, lq = o & 63;
        const int row = lq & 31, c0 = q * 16 + (lq >> 5) * 8;
        uint4 pk = *(const uint4*)&Ls[row * 520 + c0];
        *(uint4*)&wall[(size_t)tt * 16384 + (size_t)o * 8] = pk;
    }
}

// ---------------------------------------------------------------------------
// proj_v12 (r10 structure; h epilogue packs fp8 e4m3 ROW-MAJOR). grid 384, block 512.
__global__ __launch_bounds__(512, 4) void proj_kernel(
    const float* __restrict__ x,
    const unsigned short* __restrict__ wall,
    const float* __restrict__ f_b, const float* __restrict__ g_b,
    const float* __restrict__ h_b,
    unsigned short* __restrict__ fa, unsigned short* __restrict__ gbuf,
    unsigned char* __restrict__ ha)
{
    __shared__ __align__(16) unsigned short Xf[2][8192];
    const int t    = threadIdx.x;
    const int w    = t >> 6;
    const int l    = t & 63;
    const int half = l >> 5;
    const int tx = t & 15;
    const int ty = t >> 4;
    const int c0 = ty * 2;
    const int qs = c0 >> 4;
    const int woff = (c0 & 7);
    const int hfs = (c0 >> 3) & 1;

    const int blk = blockIdx.x;

    if (blk < 256) {
        // ================= h-path: 16 c-tiles x 64 n =================
        const int b  = blk >> 6;
        const int nb = blk & 63;
        const int n0g = nb * 64;
        const int n0 = tx * 4;

        f32x16 acc[2][2];
        #pragma unroll
        for (int j = 0; j < 2; ++j)
            #pragma unroll
            for (int s = 0; s < 2; ++s)
                #pragma unroll
                for (int r = 0; r < 16; ++r) acc[j][s][r] = 0.f;

        const unsigned short* wp0 = wall + (size_t)(4 + w * 2) * 16384 + (size_t)l * 8;
        const unsigned short* wp1 = wp0 + 16384;
        bf16x8 wc0 = *(const bf16x8*)wp0;
        bf16x8 wc1 = *(const bf16x8*)wp1;

        float4 v0 = *(const float4*)&x[((size_t)(b * C_IN + c0)) * N_PIX + n0g + n0];
        float4 v1 = *(const float4*)&x[((size_t)(b * C_IN + c0 + 1)) * N_PIX + n0g + n0];

        for (int it = 0; it < 8; ++it) {
            {
                unsigned short* xb = &Xf[it & 1][0];
                const float a0[4] = {v0.x, v0.y, v0.z, v0.w};
                const float a1[4] = {v1.x, v1.y, v1.z, v1.w};
                #pragma unroll
                for (int j = 0; j < 4; ++j) {
                    const int n = n0 + j;
                    const int off = ((n >> 5) * 4 + qs) * 512
                                  + ((n & 31) + 32 * hfs) * 8 + woff;
                    *(unsigned*)&xb[off] = cvt_pk_bf16(a0[j], a1[j]);
                }
            }
            if (it < 7) {
                v0 = *(const float4*)&x[((size_t)(b * C_IN + (it + 1) * 64 + c0)) * N_PIX + n0g + n0];
                v1 = *(const float4*)&x[((size_t)(b * C_IN + (it + 1) * 64 + c0 + 1)) * N_PIX + n0g + n0];
            }
            __syncthreads();
            const unsigned short* xb = &Xf[it & 1][0];
            #pragma unroll
            for (int q = 0; q < 4; ++q) {
                const int qn = (it * 4 + q + 1) & 31;
                bf16x8 wn0 = *(const bf16x8*)(wp0 + (size_t)qn * 512);
                bf16x8 wn1 = *(const bf16x8*)(wp1 + (size_t)qn * 512);
                bf16x8 x0 = *(const bf16x8*)&xb[(0 * 4 + q) * 512 + l * 8];
                bf16x8 x1 = *(const bf16x8*)&xb[(1 * 4 + q) * 512 + l * 8];
                acc[0][0] = __builtin_amdgcn_mfma_f32_32x32x16_bf16(x0, wc0, acc[0][0], 0, 0, 0);
                acc[0][1] = __builtin_amdgcn_mfma_f32_32x32x16_bf16(x1, wc0, acc[0][1], 0, 0, 0);
                acc[1][0] = __builtin_amdgcn_mfma_f32_32x32x16_bf16(x0, wc1, acc[1][0], 0, 0, 0);
                acc[1][1] = __builtin_amdgcn_mfma_f32_32x32x16_bf16(x1, wc1, acc[1][1], 0, 0, 0);
                wc0 = wn0; wc1 = wn1;
            }
            __syncthreads();
        }

        // epilogue: pack fp8 e4m3 ROW-MAJOR into ha[b][c][4096].
        // D-frag: channel = lane&31 (per ctile), n_local = ns*32 + 8*j2 + 4*half + rr
        #pragma unroll
        for (int j = 0; j < 2; ++j) {
            const int ctile = w * 2 + j;
            const int ch = ctile * 32 + (l & 31);
            const float hb = h_b[ch];
            unsigned char* hrow = ha + ((size_t)(b * C_IN + ch)) * N_PIX + n0g + 4 * half;
            #pragma unroll
            for (int ns = 0; ns < 2; ++ns) {
                #pragma unroll
                for (int j2 = 0; j2 < 4; ++j2) {
                    unsigned pk = pk_fp8x4(acc[j][ns][4 * j2 + 0] + hb,
                                           acc[j][ns][4 * j2 + 1] + hb,
                                           acc[j][ns][4 * j2 + 2] + hb,
                                           acc[j][ns][4 * j2 + 3] + hb);
                    *(unsigned*)&hrow[ns * 32 + j2 * 8] = pk;
                }
            }
        }
    } else {
        // ================= fg-path: 4 tiles x 128 n (bf16, unchanged) =======
        const int blk2 = blk - 256;
        const int b   = blk2 >> 5;
        const int nb2 = blk2 & 31;
        const int n0g = nb2 * 128;
        const int tt    = w & 3;
        const int npair = w >> 2;

        f32x16 acc[2];
        #pragma unroll
        for (int s = 0; s < 2; ++s)
            #pragma unroll
            for (int r = 0; r < 16; ++r) acc[s][r] = 0.f;

        const unsigned short* wpf = wall + (size_t)tt * 16384 + (size_t)l * 8;
        bf16x8 wcf = *(const bf16x8*)wpf;

        float4 v00 = *(const float4*)&x[((size_t)(b * C_IN + c0)) * N_PIX + n0g + tx * 4];
        float4 v10 = *(const float4*)&x[((size_t)(b * C_IN + c0 + 1)) * N_PIX + n0g + tx * 4];
        float4 v01 = *(const float4*)&x[((size_t)(b * C_IN + c0)) * N_PIX + n0g + 64 + tx * 4];
        float4 v11 = *(const float4*)&x[((size_t)(b * C_IN + c0 + 1)) * N_PIX + n0g + 64 + tx * 4];

        for (int it = 0; it < 8; ++it) {
            {
                unsigned short* xb = &Xf[it & 1][0];
                const float a00[4] = {v00.x, v00.y, v00.z, v00.w};
                const float a10[4] = {v10.x, v10.y, v10.z, v10.w};
                const float a01[4] = {v01.x, v01.y, v01.z, v01.w};
                const float a11[4] = {v11.x, v11.y, v11.z, v11.w};
                #pragma unroll
                for (int j = 0; j < 4; ++j) {
                    const int n = tx * 4 + j;
                    const int off0 = ((n >> 5) * 4 + qs) * 512
                                   + ((n & 31) + 32 * hfs) * 8 + woff;
                    *(unsigned*)&xb[off0] = cvt_pk_bf16(a00[j], a10[j]);
                    const int n2 = 64 + n;
                    const int off1 = ((n2 >> 5) * 4 + qs) * 512
                                   + ((n2 & 31) + 32 * hfs) * 8 + woff;
                    *(unsigned*)&xb[off1] = cvt_pk_bf16(a01[j], a11[j]);
                }
            }
            if (it < 7) {
                const size_t rb = (size_t)(b * C_IN + (it + 1) * 64 + c0) * N_PIX + n0g;
                v00 = *(const float4*)&x[rb + tx * 4];
                v10 = *(const float4*)&x[rb + N_PIX + tx * 4];
                v01 = *(const float4*)&x[rb + 64 + tx * 4];
                v11 = *(const float4*)&x[rb + N_PIX + 64 + tx * 4];
            }
            __syncthreads();
            const unsigned short* xb = &Xf[it & 1][0];
            #pragma unroll
            for (int q = 0; q < 4; ++q) {
                const int qn = (it * 4 + q + 1) & 31;
                bf16x8 wnf = *(const bf16x8*)(wpf + (size_t)qn * 512);
                bf16x8 x0 = *(const bf16x8*)&xb[((npair * 2 + 0) * 4 + q) * 512 + l * 8];
                bf16x8 x1 = *(const bf16x8*)&xb[((npair * 2 + 1) * 4 + q) * 512 + l * 8];
                acc[0] = __builtin_amdgcn_mfma_f32_32x32x16_bf16(wcf, x0, acc[0], 0, 0, 0);
                acc[1] = __builtin_amdgcn_mfma_f32_32x32x16_bf16(wcf, x1, acc[1], 0, 0, 0);
                wcf = wnf;
            }
            __syncthreads();
        }

        unsigned short* buf = (tt < 2) ? fa : gbuf;
        const float* bias = (tt < 2) ? f_b : g_b;
        #pragma unroll
        for (int s = 0; s < 2; ++s) {
            const int ntile = nb2 * 4 + npair * 2 + s;
            #pragma unroll
            for (int j2 = 0; j2 < 4; ++j2) {
                const int o_base = (tt & 1) * 32 + 8 * j2 + 4 * half;
                float4 bv = *(const float4*)&bias[o_base];
                const int q  = o_base >> 4;
                const int lp = (l & 31) + 32 * (j2 & 1);
                uint2 pk;
                pk.x = cvt_pk_bf16(acc[s][4 * j2 + 0] + bv.x, acc[s][4 * j2 + 1] + bv.y);
                pk.y = cvt_pk_bf16(acc[s][4 * j2 + 2] + bv.z, acc[s][4 * j2 + 3] + bv.w);
                size_t off = (((size_t)(b * 128 + ntile) * 4 + q) * 64 + lp) * 8 + 4 * half;
                *(uint2*)&buf[off] = pk;
            }
        }
    }
}

// ---------------------------------------------------------------------------
// attn: r7 structure; PV via MX fp8 mfma_scale 32x32x64 (unit scales),
// S in bf16. grid 512, block 512.
__global__ __launch_bounds__(512, 4) void attn_kernel(
    const unsigned short* __restrict__ fa,
    const unsigned short* __restrict__ gbuf,
    const unsigned char* __restrict__ ha,
    const float* __restrict__ x,
    const float* __restrict__ gamma_p,
    float* __restrict__ out)
{
    __shared__ __align__(16) unsigned char Ebuf[2][64 * 136];  // 17.4 KB (fp8 E)
    __shared__ __align__(16) unsigned short Fst[2][16 * 512];  // 32 KB f staging
    __shared__ float den_part[4][64];
    __shared__ float den_inv[64];

    const int t    = threadIdx.x;
    const int w    = t >> 6;
    const int l    = t & 63;
    const int lane = l & 31;
    const int half = l >> 5;
    const int nsub = w & 3;
    const int mt   = w >> 2;

    const int blk   = blockIdx.x;
    const int chalf = blk & 1;
    const int b     = (blk >> 1) & 3;
    const int mi    = blk >> 3;
    const int m0    = mi * 64;

    bf16x8 gfrag[4];
    {
        const unsigned short* gp = gbuf
            + ((size_t)(b * 128 + mi * 2 + mt) * 4) * 512 + (size_t)l * 8;
        #pragma unroll
        for (int q = 0; q < 4; ++q)
            gfrag[q] = *(const bf16x8*)(gp + (size_t)q * 512);
    }

    f32x16 acc[2];
    #pragma unroll
    for (int j = 0; j < 2; ++j)
        #pragma unroll
        for (int r = 0; r < 16; ++r) acc[j][r] = 0.f;

    float denp = 0.f;

    const unsigned short* fbase = fa + (size_t)b * (128 * 4) * 512;
    const int ctg = chalf * 8 + w;
    // row-major h: lane's row = channel ctg*32 + lane, 64-wide A-frag wants
    // n = nt*128 + kt*64 + half*32 + i (32 consecutive bytes per lane).
    const unsigned char* hbase = ha
        + ((size_t)(b * C_IN + ctg * 32 + lane)) * N_PIX + (size_t)half * 32;

    #pragma unroll
    for (int j = 0; j < 2; ++j) {
        const int chunk = w * 2 + j;
        const unsigned short* src = fbase
            + ((size_t)((chunk >> 2)) * 4 + (chunk & 3)) * 512 + (size_t)l * 8;
        gload_lds16(src, &Fst[0][chunk * 512]);
    }
    __syncthreads();

    for (int nt = 0; nt < 32; ++nt) {
        if (nt < 31) {
            #pragma unroll
            for (int j = 0; j < 2; ++j) {
                const int chunk = w * 2 + j;
                const unsigned short* src = fbase
                    + ((size_t)((nt + 1) * 4 + (chunk >> 2)) * 4 + (chunk & 3)) * 512
                    + (size_t)l * 8;
                gload_lds16(src, &Fst[(nt + 1) & 1][chunk * 512]);
            }
        }
        bf16x8 ff[4];
        #pragma unroll
        for (int q = 0; q < 4; ++q)
            ff[q] = *(const bf16x8*)&Fst[nt & 1][(nsub * 4 + q) * 512 + l * 8];
        f32x16 s;
        #pragma unroll
        for (int r = 0; r < 16; ++r) s[r] = 0.f;
        #pragma unroll
        for (int q = 0; q < 4; ++q)
            s = __builtin_amdgcn_mfma_f32_32x32x16_bf16(ff[q], gfrag[q], s, 0, 0, 0);
        // E' = exp(s - 6), clamped so e4m3 never overflows (448); the e^-6
        // scale cancels between numerator and denominator.
        unsigned char* ew = &Ebuf[nt & 1][(mt * 32 + lane) * 136 + nsub * 32 + half * 4];
        #pragma unroll
        for (int r4 = 0; r4 < 4; ++r4) {
            float e0 = __expf(fminf(s[r4 * 4 + 0] - 6.0f, 6.0f));
            float e1 = __expf(fminf(s[r4 * 4 + 1] - 6.0f, 6.0f));
            float e2 = __expf(fminf(s[r4 * 4 + 2] - 6.0f, 6.0f));
            float e3 = __expf(fminf(s[r4 * 4 + 3] - 6.0f, 6.0f));
            denp += (e0 + e1) + (e2 + e3);
            *(unsigned*)(ew + r4 * 8) = pk_fp8x4(e0, e1, e2, e3);
        }
        // A-frags for the two 64-wide k-blocks of this nt (32B/lane each)
        i32x8 a0, a1;
        {
            const unsigned char* hp = hbase + (size_t)nt * 128;
            a0 = *(const i32x8*)hp;
            a1 = *(const i32x8*)(hp + 64);
        }
        __syncthreads();
        const unsigned char* eb = &Ebuf[nt & 1][0];
        #pragma unroll
        for (int kt = 0; kt < 2; ++kt) {
            // B-frag: col = lane (m), k = kt*64 + half*32 + i from m-major Ebuf.
            const unsigned char* e0 = eb + lane * 136 + kt * 64 + half * 32;
            union { i32x8 v; long d[4]; } b0, b1;
            #pragma unroll
            for (int j = 0; j < 4; ++j) {
                b0.d[j] = *(const long*)(e0 + 8 * j);
                b1.d[j] = *(const long*)(e0 + 32 * 136 + 8 * j);
            }
            const i32x8 av = kt ? a1 : a0;
            acc[0] = __builtin_amdgcn_mfma_scale_f32_32x32x64_f8f6f4(
                av, b0.v, acc[0], 0, 0, 0, 127, 0, 127);
            acc[1] = __builtin_amdgcn_mfma_scale_f32_32x32x64_f8f6f4(
                av, b1.v, acc[1], 0, 0, 0, 127, 0, 127);
        }
    }

    denp += __shfl_xor(denp, 32, 64);
    if (l < 32) den_part[nsub][mt * 32 + lane] = denp;
    __syncthreads();
    if (t < 64) {
        float d = den_part[0][t] + den_part[1][t] + den_part[2][t] + den_part[3][t];
        den_inv[t] = 1.0f / d;
    }
    __syncthreads();

    const float gs = gamma_p[0];
    #pragma unroll
    for (int mt2 = 0; mt2 < 2; ++mt2) {
        const int mloc = mt2 * 32 + lane;
        const float dinv = den_inv[mloc];
        const int m = m0 + mloc;
        #pragma unroll
        for (int r = 0; r < 16; ++r) {
            const int c = ctg * 32 + (r & 3) + ((r >> 2) * 8) + half * 4;
            const size_t idx = ((size_t)(b * C_IN + c)) * N_PIX + m;
            out[idx] = gs * acc[mt2][r] * dinv + x[idx];
        }
    }
}

// ---------------------------------------------------------------------------
extern "C" void kernel_launch(void* const* d_in, const int* in_sizes, int n_in,
                              void* d_out, int out_size, void* d_ws, size_t ws_size,
                              hipStream_t stream)
{
    const float* x     = (const float*)d_in[0];
    const float* f_w   = (const float*)d_in[1];
    const float* f_b   = (const float*)d_in[2];
    const float* g_w   = (const float*)d_in[3];
    const float* g_b   = (const float*)d_in[4];
    const float* h_w   = (const float*)d_in[5];
    const float* h_b   = (const float*)d_in[6];
    const float* gamma = (const float*)d_in[7];
    float* out = (float*)d_out;

    unsigned short* fa   = (unsigned short*)d_ws;        // 1M shorts (2 MB)
    unsigned short* gbuf = fa + (1u << 20);              // 1M shorts (2 MB)
    unsigned char*  ha   = (unsigned char*)(gbuf + (1u << 20));  // 8 MB fp8 row-major
    unsigned short* wall = (unsigned short*)(ha + (8u << 20));   // 640 KB

    pack_w<<<20, 256, 0, stream>>>(f_w, g_w, h_w, wall);

    proj_kernel<<<384, 512, 0, stream>>>(x, wall, f_b, g_b, h_b, fa, gbuf, ha);

    attn_kernel<<<512, 512, 0, stream>>>(fa, gbuf, ha, x, gamma, out);
}